// Round 4
// baseline (880.424 us; speedup 1.0000x reference)
//
#include <hip/hip_runtime.h>
#include <stdint.h>

// Problem constants (B=4, L=2048, D=1024, H=16, DPH=64)
// Harness dtypes: float inputs FLOAT32, attn_mask INT32, outputs FLOAT32
// (reference returns f32; comparison is bf16-rounded-ref with 2% threshold).

typedef unsigned short u16;
typedef __attribute__((ext_vector_type(8))) short short8;   // 8 bf16 = one MFMA A/B frag
typedef __attribute__((ext_vector_type(4))) float f32x4;    // MFMA C/D frag
typedef __attribute__((ext_vector_type(4))) float float4v;

__device__ __forceinline__ u16 f2bf(float f){
  union { float f; uint32_t i; } c; c.f = f;
  return (u16)((c.i + 0x7FFFu + ((c.i >> 16) & 1u)) >> 16);  // RNE
}
__device__ __forceinline__ short8 ld8(const u16* p){ return *(const short8*)p; }
// load 8 consecutive f32, convert to bf16 frag (staging path)
__device__ __forceinline__ short8 ld8f(const float* p){
  const float4v a = *(const float4v*)p;
  const float4v b = *(const float4v*)(p + 4);
  short8 r;
  r[0] = (short)f2bf(a[0]); r[1] = (short)f2bf(a[1]);
  r[2] = (short)f2bf(a[2]); r[3] = (short)f2bf(a[3]);
  r[4] = (short)f2bf(b[0]); r[5] = (short)f2bf(b[1]);
  r[6] = (short)f2bf(b[2]); r[7] = (short)f2bf(b[3]);
  return r;
}

#define MFMA(a,b,c) __builtin_amdgcn_mfma_f32_16x16x32_bf16((a),(b),(c),0,0,0)

// ---------------------------------------------------------------------------
// Diagnostic: if workspace is too small, encode ws_size (MB) into out[0].
__global__ void sentinel_k(float* out, float v){ out[0] = v; }

// ---------------------------------------------------------------------------
// Kernel 0: pack int32 mask (B,L,L) into bit words (B,L,L/64). bit=1 => masked.
__global__ __launch_bounds__(256) void maskpack_k(const int* __restrict__ m,
                                                  uint64_t* __restrict__ bits){
  int t = blockIdx.x * 256 + threadIdx.x;
  uint64_t b = __ballot(m[t] != 0);
  if ((threadIdx.x & 63) == 0) bits[t >> 6] = b;
}

// ---------------------------------------------------------------------------
// Kernel 1: QKV projection (f32 in, bf16 out). z=0: kp, z=1: qp, z=2: vp (transposed).
// C[r,c] = sum_d A[r,d] * W[c,d] + bias[c]
__global__ __launch_bounds__(256) void qkv_gemm_k(
    const float* __restrict__ kin, const float* __restrict__ qin, const float* __restrict__ vin,
    const float* __restrict__ w, const float* __restrict__ bias,
    u16* __restrict__ qh, u16* __restrict__ kh, u16* __restrict__ vt)
{
  const int z = blockIdx.z;
  const float* A = (z == 0) ? kin : (z == 1) ? qin : vin;
  const float* W = w + (size_t)z * 1024 * 1024;
  const float* bs = bias + z * 1024;
  const int tileM = blockIdx.y * 64, tileN = blockIdx.x * 64;
  __shared__ __align__(16) u16 As[64 * 32];
  __shared__ __align__(16) u16 Bs[64 * 32];
  const int t = threadIdx.x, wave = t >> 6, lane = t & 63, quad = lane >> 4, mm = lane & 15;
  const int waveM = (wave >> 1) * 32, waveN = (wave & 1) * 32;
  f32x4 acc[2][2];
  for (int i = 0; i < 2; i++) for (int j = 0; j < 2; j++) acc[i][j] = (f32x4){0.f,0.f,0.f,0.f};
  const int lr = t >> 2, lc = (t & 3) * 8;
  for (int k0 = 0; k0 < 1024; k0 += 32){
    __syncthreads();
    *(short8*)&As[lr * 32 + lc] = ld8f(&A[(size_t)(tileM + lr) * 1024 + k0 + lc]);
    *(short8*)&Bs[lr * 32 + lc] = ld8f(&W[(size_t)(tileN + lr) * 1024 + k0 + lc]);
    __syncthreads();
    short8 a0 = *(const short8*)&As[(waveM + mm) * 32 + quad * 8];
    short8 a1 = *(const short8*)&As[(waveM + 16 + mm) * 32 + quad * 8];
    short8 b0 = *(const short8*)&Bs[(waveN + mm) * 32 + quad * 8];
    short8 b1 = *(const short8*)&Bs[(waveN + 16 + mm) * 32 + quad * 8];
    acc[0][0] = MFMA(a0, b0, acc[0][0]);
    acc[0][1] = MFMA(a0, b1, acc[0][1]);
    acc[1][0] = MFMA(a1, b0, acc[1][0]);
    acc[1][1] = MFMA(a1, b1, acc[1][1]);
  }
  for (int i = 0; i < 2; i++) for (int j = 0; j < 2; j++){
    int col = tileN + waveN + j * 16 + mm;
    float bv = bs[col];
    int h = col >> 6, d = col & 63;
    for (int r = 0; r < 4; r++){
      int row = tileM + waveM + i * 16 + quad * 4 + r;
      int bb = row >> 11, l = row & 2047;
      float v = acc[i][j][r] + bv;
      if (z == 2)      vt[((bb * 16 + h) * 64 + d) * 2048 + l] = f2bf(v);
      else if (z == 1) qh[((bb * 16 + h) * 2048 + l) * 64 + d] = f2bf(v);
      else             kh[((bb * 16 + h) * 2048 + l) * 64 + d] = f2bf(v);
    }
  }
}

// ---------------------------------------------------------------------------
// Kernel 2: flash attention. One block = 64 q-rows of one (b,h). Writes merged
// context [b,l,1024] (bf16 scratch) and per-row softmax stats (m, l).
// S scaled by 0.125 post-MFMA (Q stored unscaled).
__global__ __launch_bounds__(256) void flash_k(
    const u16* __restrict__ qh, const u16* __restrict__ kh, const u16* __restrict__ vt,
    const uint64_t* __restrict__ maskbits, u16* __restrict__ ctx,
    float* __restrict__ statsM, float* __restrict__ statsL)
{
  const int b = blockIdx.z, h = blockIdx.y, q0 = blockIdx.x * 64;
  const int t = threadIdx.x, wave = t >> 6, lane = t & 63, quad = lane >> 4, mm = lane & 15;
  __shared__ __align__(16) u16 Ks[64 * 64];          // [key][d]
  __shared__ __align__(16) u16 Vs[64 * 64];          // [d][key]  (from vt)
  __shared__ __align__(16) u16 Ps[4][16 * 64];       // per-wave P: [q][key]
  const u16* qb = qh + (size_t)((b * 16 + h) * 2048) * 64;
  const u16* kb = kh + (size_t)((b * 16 + h) * 2048) * 64;
  const u16* vb = vt + (size_t)((b * 16 + h) * 64) * 2048;
  const int qrow = q0 + wave * 16 + mm;
  short8 qa0 = ld8(&qb[qrow * 64 + quad * 8]);
  short8 qa1 = ld8(&qb[qrow * 64 + 32 + quad * 8]);
  f32x4 O[4];
  float mr[4], lrn[4];
  for (int cb = 0; cb < 4; cb++) O[cb] = (f32x4){0.f,0.f,0.f,0.f};
  for (int r = 0; r < 4; r++){ mr[r] = -1e30f; lrn[r] = 0.f; }
  const int lr_ = t >> 2, lc_ = (t & 3) * 8;
  const int qg0 = q0 + wave * 16 + quad * 4;
  const uint64_t* mwb = maskbits + (size_t)(b * 2048) * 32;
  u16* Pw = &Ps[wave][0];

  for (int kt = 0; kt < 32; kt++){
    const int k0 = kt * 64;
    __syncthreads();
    *(short8*)&Ks[lr_ * 64 + lc_]      = ld8(&kb[(k0 + lr_) * 64 + lc_]);
    *(short8*)&Ks[lr_ * 64 + 32 + lc_] = ld8(&kb[(k0 + lr_) * 64 + 32 + lc_]);
    *(short8*)&Vs[lr_ * 64 + lc_]      = ld8(&vb[lr_ * 2048 + k0 + lc_]);
    *(short8*)&Vs[lr_ * 64 + 32 + lc_] = ld8(&vb[lr_ * 2048 + k0 + 32 + lc_]);
    __syncthreads();
    // S = 0.125 * Q K^T
    f32x4 S[4];
    for (int cb = 0; cb < 4; cb++){
      S[cb] = (f32x4){0.f,0.f,0.f,0.f};
      short8 kb0 = *(const short8*)&Ks[(cb * 16 + mm) * 64 + quad * 8];
      short8 kb1 = *(const short8*)&Ks[(cb * 16 + mm) * 64 + 32 + quad * 8];
      S[cb] = MFMA(qa0, kb0, S[cb]);
      S[cb] = MFMA(qa1, kb1, S[cb]);
      for (int r = 0; r < 4; r++) S[cb][r] *= 0.125f;
    }
    // mask: bit set => masked
    uint64_t wb[4];
    for (int r = 0; r < 4; r++) wb[r] = mwb[(size_t)(qg0 + r) * 32 + (k0 >> 6)];
    for (int cb = 0; cb < 4; cb++)
      for (int r = 0; r < 4; r++)
        if ((wb[r] >> (cb * 16 + mm)) & 1ull) S[cb][r] = -1e30f;
    // online softmax per row r (16 lanes of same quad hold one row)
    for (int r = 0; r < 4; r++){
      float tmax = fmaxf(fmaxf(S[0][r], S[1][r]), fmaxf(S[2][r], S[3][r]));
      for (int off = 1; off < 16; off <<= 1) tmax = fmaxf(tmax, __shfl_xor(tmax, off, 64));
      float mnew  = fmaxf(mr[r], tmax);
      float alpha = __expf(mr[r] - mnew);
      float tsum = 0.f;
      for (int cb = 0; cb < 4; cb++){
        float p = (S[cb][r] > -1e29f) ? __expf(S[cb][r] - mnew) : 0.f;
        S[cb][r] = p; tsum += p;
      }
      for (int off = 1; off < 16; off <<= 1) tsum += __shfl_xor(tsum, off, 64);
      lrn[r] = lrn[r] * alpha + tsum;
      mr[r]  = mnew;
      for (int cb = 0; cb < 4; cb++) O[cb][r] *= alpha;
    }
    // P (C-layout) -> LDS (bf16) -> A-layout frags
    for (int cb = 0; cb < 4; cb++)
      for (int r = 0; r < 4; r++)
        Pw[(quad * 4 + r) * 64 + cb * 16 + mm] = f2bf(S[cb][r]);
    for (int s = 0; s < 2; s++){
      short8 pa = *(const short8*)&Pw[mm * 64 + s * 32 + quad * 8];
      for (int cb = 0; cb < 4; cb++){
        short8 vv = *(const short8*)&Vs[(cb * 16 + mm) * 64 + s * 32 + quad * 8];
        O[cb] = MFMA(pa, vv, O[cb]);
      }
    }
  }
  float inv[4];
  for (int r = 0; r < 4; r++) inv[r] = (lrn[r] > 0.f) ? 1.0f / lrn[r] : 0.f;
  for (int cb = 0; cb < 4; cb++)
    for (int r = 0; r < 4; r++){
      int qg = qg0 + r;
      ctx[(size_t)(b * 2048 + qg) * 1024 + h * 64 + cb * 16 + mm] = f2bf(O[cb][r] * inv[r]);
    }
  if (mm == 0){
    for (int r = 0; r < 4; r++){
      statsM[(b * 16 + h) * 2048 + qg0 + r] = mr[r];
      statsL[(b * 16 + h) * 2048 + qg0 + r] = lrn[r];
    }
  }
}

// ---------------------------------------------------------------------------
// Kernel 3: attn_avg[b,q,k] = qmask[b,q] * (1/16) sum_h exp(S-m)/l   (f32 out)
__global__ __launch_bounds__(256) void attnavg_k(
    const u16* __restrict__ qh, const u16* __restrict__ kh,
    const uint64_t* __restrict__ maskbits, const float* __restrict__ statsM,
    const float* __restrict__ statsL, const float* __restrict__ qmask,
    float* __restrict__ out2)
{
  const int b = blockIdx.z, q0 = blockIdx.y * 64, k0 = blockIdx.x * 64;
  const int t = threadIdx.x, wave = t >> 6, lane = t & 63, quad = lane >> 4, mm = lane & 15;
  __shared__ __align__(16) u16 Ks[64 * 64];
  f32x4 acc[4];
  for (int cb = 0; cb < 4; cb++) acc[cb] = (f32x4){0.f,0.f,0.f,0.f};
  const int qg0 = q0 + wave * 16 + quad * 4;
  uint64_t wb[4];
  for (int r = 0; r < 4; r++)
    wb[r] = maskbits[(size_t)(b * 2048 + qg0 + r) * 32 + (k0 >> 6)];
  const int lr_ = t >> 2, lc_ = (t & 3) * 8;

  for (int h = 0; h < 16; h++){
    const u16* kb = kh + (size_t)((b * 16 + h) * 2048) * 64;
    const u16* qb = qh + (size_t)((b * 16 + h) * 2048) * 64;
    __syncthreads();
    *(short8*)&Ks[lr_ * 64 + lc_]      = ld8(&kb[(k0 + lr_) * 64 + lc_]);
    *(short8*)&Ks[lr_ * 64 + 32 + lc_] = ld8(&kb[(k0 + lr_) * 64 + 32 + lc_]);
    __syncthreads();
    const int qrow = q0 + wave * 16 + mm;
    short8 qa0 = ld8(&qb[qrow * 64 + quad * 8]);
    short8 qa1 = ld8(&qb[qrow * 64 + 32 + quad * 8]);
    f32x4 S[4];
    for (int cb = 0; cb < 4; cb++){
      S[cb] = (f32x4){0.f,0.f,0.f,0.f};
      short8 kb0 = *(const short8*)&Ks[(cb * 16 + mm) * 64 + quad * 8];
      short8 kb1 = *(const short8*)&Ks[(cb * 16 + mm) * 64 + 32 + quad * 8];
      S[cb] = MFMA(qa0, kb0, S[cb]);
      S[cb] = MFMA(qa1, kb1, S[cb]);
      for (int r = 0; r < 4; r++) S[cb][r] *= 0.125f;
    }
    for (int r = 0; r < 4; r++){
      int sidx = (b * 16 + h) * 2048 + qg0 + r;
      float mh = statsM[sidx], lh = statsL[sidx];
      float sc = (lh > 0.f) ? 1.0f / (lh * 16.0f) : 0.f;
      for (int cb = 0; cb < 4; cb++)
        if (!((wb[r] >> (cb * 16 + mm)) & 1ull))
          acc[cb][r] += __expf(S[cb][r] - mh) * sc;
    }
  }
  for (int r = 0; r < 4; r++){
    int qg = qg0 + r;
    float qm = qmask[b * 2048 + qg];
    for (int cb = 0; cb < 4; cb++)
      out2[(size_t)(b * 2048 + qg) * 2048 + k0 + cb * 16 + mm] = acc[cb][r] * qm;
  }
}

// ---------------------------------------------------------------------------
// Kernel 4: final projection (f32 out). out[r,c] = qmask[r]*(sum_d ctx[r,d]*finw[c,d]+b[c])
__global__ __launch_bounds__(256) void fin_gemm_k(
    const u16* __restrict__ A, const float* __restrict__ W, const float* __restrict__ bias,
    const float* __restrict__ qmask, float* __restrict__ out)
{
  const int tileM = blockIdx.y * 64, tileN = blockIdx.x * 64;
  __shared__ __align__(16) u16 As[64 * 32];
  __shared__ __align__(16) u16 Bs[64 * 32];
  const int t = threadIdx.x, wave = t >> 6, lane = t & 63, quad = lane >> 4, mm = lane & 15;
  const int waveM = (wave >> 1) * 32, waveN = (wave & 1) * 32;
  f32x4 acc[2][2];
  for (int i = 0; i < 2; i++) for (int j = 0; j < 2; j++) acc[i][j] = (f32x4){0.f,0.f,0.f,0.f};
  const int lr = t >> 2, lc = (t & 3) * 8;
  for (int k0 = 0; k0 < 1024; k0 += 32){
    __syncthreads();
    *(short8*)&As[lr * 32 + lc] = ld8(&A[(size_t)(tileM + lr) * 1024 + k0 + lc]);
    *(short8*)&Bs[lr * 32 + lc] = ld8f(&W[(size_t)(tileN + lr) * 1024 + k0 + lc]);
    __syncthreads();
    short8 a0 = *(const short8*)&As[(waveM + mm) * 32 + quad * 8];
    short8 a1 = *(const short8*)&As[(waveM + 16 + mm) * 32 + quad * 8];
    short8 b0 = *(const short8*)&Bs[(waveN + mm) * 32 + quad * 8];
    short8 b1 = *(const short8*)&Bs[(waveN + 16 + mm) * 32 + quad * 8];
    acc[0][0] = MFMA(a0, b0, acc[0][0]);
    acc[0][1] = MFMA(a0, b1, acc[0][1]);
    acc[1][0] = MFMA(a1, b0, acc[1][0]);
    acc[1][1] = MFMA(a1, b1, acc[1][1]);
  }
  for (int i = 0; i < 2; i++) for (int j = 0; j < 2; j++){
    int col = tileN + waveN + j * 16 + mm;
    float bv = bias[col];
    for (int r = 0; r < 4; r++){
      int row = tileM + waveM + i * 16 + quad * 4 + r;
      float v = (acc[i][j][r] + bv) * qmask[row];
      out[(size_t)row * 1024 + col] = v;
    }
  }
}

// ---------------------------------------------------------------------------
extern "C" void kernel_launch(void* const* d_in, const int* in_sizes, int n_in,
                              void* d_out, int out_size, void* d_ws, size_t ws_size,
                              hipStream_t stream) {
  // setup_inputs order: k, v, q, attn_mask, query_mask, kqv_w, kqv_b, fin_w, fin_b
  const float* k_in   = (const float*)d_in[0];
  const float* v_in   = (const float*)d_in[1];
  const float* q_in   = (const float*)d_in[2];
  const int*   amask  = (const int*)d_in[3];
  const float* qmask  = (const float*)d_in[4];
  const float* kqv_w  = (const float*)d_in[5];
  const float* kqv_b  = (const float*)d_in[6];
  const float* fin_w  = (const float*)d_in[7];
  const float* fin_b  = (const float*)d_in[8];
  float* out  = (float*)d_out;                  // out0: [0, 8388608) context (f32)
  float* out2 = out + (size_t)8388608;          // out1: attn_avg (16777216 f32)

  // ws diagnostic: if too small, encode ws_size into out[0] -> absmax ~ 1e6+MB.
  const size_t WS_NEED = 36700160;
  if (ws_size < WS_NEED){
    sentinel_k<<<1, 1, 0, stream>>>(out, 1.0e6f + (float)(ws_size >> 20));
    return;
  }

  // Scratch: 36.7 MB in d_ws; bf16 intermediates parked inside f32 d_out:
  //   vt  (V^T, bf16, 16.7MB)  -> out0 region (33.5MB; fin_gemm overwrites later)
  //   ctx (pre-proj, bf16, 16.7MB) -> out2 region (67MB; attnavg overwrites later)
  // Order: maskpack -> qkv -> flash -> fin_gemm (reads ctx) -> attnavg.
  u16* qh  = (u16*)d_ws;                        // 8,388,608 bf16 (16.7 MB)
  u16* kh  = qh + (size_t)8388608;              // 16.7 MB
  float* statsM = (float*)(kh + (size_t)8388608);    // B*H*L = 131072 f32
  float* statsL = statsM + 131072;
  uint64_t* maskbits = (uint64_t*)(statsL + 131072); // B*L*32 words (2 MB)
  u16* vt  = (u16*)out;                         // scratch in out0
  u16* ctx = (u16*)out2;                        // scratch in out2 (first 16.7MB)

  maskpack_k<<<dim3(65536), dim3(256), 0, stream>>>(amask, maskbits);
  qkv_gemm_k<<<dim3(16, 128, 3), dim3(256), 0, stream>>>(
      k_in, q_in, v_in, kqv_w, kqv_b, qh, kh, vt);
  flash_k<<<dim3(32, 16, 4), dim3(256), 0, stream>>>(
      qh, kh, vt, maskbits, ctx, statsM, statsL);
  fin_gemm_k<<<dim3(16, 128), dim3(256), 0, stream>>>(
      ctx, fin_w, fin_b, qmask, out);
  attnavg_k<<<dim3(32, 32, 4), dim3(256), 0, stream>>>(
      qh, kh, maskbits, statsM, statsL, qmask, out2);
}

// Round 5
// 834.747 us; speedup vs baseline: 1.0547x; 1.0547x over previous
//
#include <hip/hip_runtime.h>
#include <stdint.h>

// Problem constants (B=4, L=2048, D=1024, H=16, DPH=64)
// Harness dtypes: float inputs FLOAT32, attn_mask INT32, outputs FLOAT32.
// All LDS tiles use padded row strides (odd multiple of 8 u16) to break
// power-of-2 bank aliasing: 16-way -> 2-way (free, m136).

typedef unsigned short u16;
typedef __attribute__((ext_vector_type(8))) short short8;   // 8 bf16 = one MFMA A/B frag
typedef __attribute__((ext_vector_type(4))) float f32x4;    // MFMA C/D frag
typedef __attribute__((ext_vector_type(4))) float float4v;

__device__ __forceinline__ u16 f2bf(float f){
  union { float f; uint32_t i; } c; c.f = f;
  return (u16)((c.i + 0x7FFFu + ((c.i >> 16) & 1u)) >> 16);  // RNE
}
__device__ __forceinline__ short8 ld8(const u16* p){ return *(const short8*)p; }
// load 8 consecutive f32, convert to bf16 frag (staging path)
__device__ __forceinline__ short8 ld8f(const float* p){
  const float4v a = *(const float4v*)p;
  const float4v b = *(const float4v*)(p + 4);
  short8 r;
  r[0] = (short)f2bf(a[0]); r[1] = (short)f2bf(a[1]);
  r[2] = (short)f2bf(a[2]); r[3] = (short)f2bf(a[3]);
  r[4] = (short)f2bf(b[0]); r[5] = (short)f2bf(b[1]);
  r[6] = (short)f2bf(b[2]); r[7] = (short)f2bf(b[3]);
  return r;
}

#define MFMA(a,b,c) __builtin_amdgcn_mfma_f32_16x16x32_bf16((a),(b),(c),0,0,0)

// ---------------------------------------------------------------------------
__global__ void sentinel_k(float* out, float v){ out[0] = v; }

// ---------------------------------------------------------------------------
// Kernel 0: pack int32 mask (B,L,L) into bit words (B,L,L/64). bit=1 => masked.
__global__ __launch_bounds__(256) void maskpack_k(const int* __restrict__ m,
                                                  uint64_t* __restrict__ bits){
  int t = blockIdx.x * 256 + threadIdx.x;
  uint64_t b = __ballot(m[t] != 0);
  if ((threadIdx.x & 63) == 0) bits[t >> 6] = b;
}

// ---------------------------------------------------------------------------
// Kernel 1: QKV projection (f32 in, bf16 out). z=0: kp, z=1: qp (pre-scaled by
// 0.125 -- exact in bf16), z=2: vp (transposed store).
#define QLDA 40   // padded row stride for 32-wide k-tile
__global__ __launch_bounds__(256) void qkv_gemm_k(
    const float* __restrict__ kin, const float* __restrict__ qin, const float* __restrict__ vin,
    const float* __restrict__ w, const float* __restrict__ bias,
    u16* __restrict__ qh, u16* __restrict__ kh, u16* __restrict__ vt)
{
  const int z = blockIdx.z;
  const float* A = (z == 0) ? kin : (z == 1) ? qin : vin;
  const float* W = w + (size_t)z * 1024 * 1024;
  const float* bs = bias + z * 1024;
  const int tileM = blockIdx.y * 64, tileN = blockIdx.x * 64;
  __shared__ __align__(16) u16 As[64 * QLDA];
  __shared__ __align__(16) u16 Bs[64 * QLDA];
  const int t = threadIdx.x, wave = t >> 6, lane = t & 63, quad = lane >> 4, mm = lane & 15;
  const int waveM = (wave >> 1) * 32, waveN = (wave & 1) * 32;
  f32x4 acc[2][2];
  for (int i = 0; i < 2; i++) for (int j = 0; j < 2; j++) acc[i][j] = (f32x4){0.f,0.f,0.f,0.f};
  const int lr = t >> 2, lc = (t & 3) * 8;
  for (int k0 = 0; k0 < 1024; k0 += 32){
    __syncthreads();
    *(short8*)&As[lr * QLDA + lc] = ld8f(&A[(size_t)(tileM + lr) * 1024 + k0 + lc]);
    *(short8*)&Bs[lr * QLDA + lc] = ld8f(&W[(size_t)(tileN + lr) * 1024 + k0 + lc]);
    __syncthreads();
    short8 a0 = *(const short8*)&As[(waveM + mm) * QLDA + quad * 8];
    short8 a1 = *(const short8*)&As[(waveM + 16 + mm) * QLDA + quad * 8];
    short8 b0 = *(const short8*)&Bs[(waveN + mm) * QLDA + quad * 8];
    short8 b1 = *(const short8*)&Bs[(waveN + 16 + mm) * QLDA + quad * 8];
    acc[0][0] = MFMA(a0, b0, acc[0][0]);
    acc[0][1] = MFMA(a0, b1, acc[0][1]);
    acc[1][0] = MFMA(a1, b0, acc[1][0]);
    acc[1][1] = MFMA(a1, b1, acc[1][1]);
  }
  const float scale = (z == 1) ? 0.125f : 1.0f;   // exact (pow2) in bf16
  for (int i = 0; i < 2; i++) for (int j = 0; j < 2; j++){
    int col = tileN + waveN + j * 16 + mm;
    float bv = bs[col];
    int h = col >> 6, d = col & 63;
    for (int r = 0; r < 4; r++){
      int row = tileM + waveM + i * 16 + quad * 4 + r;
      int bb = row >> 11, l = row & 2047;
      float v = (acc[i][j][r] + bv) * scale;
      if (z == 2)      vt[((bb * 16 + h) * 64 + d) * 2048 + l] = f2bf(v);
      else if (z == 1) qh[((bb * 16 + h) * 2048 + l) * 64 + d] = f2bf(v);
      else             kh[((bb * 16 + h) * 2048 + l) * 64 + d] = f2bf(v);
    }
  }
}

// ---------------------------------------------------------------------------
// Kernel 2: flash attention, 128-key tiles. One block = 64 q-rows of one (b,h).
// Q comes in pre-scaled. Writes merged context (bf16 scratch) + (m,l) stats.
#define LDK 72    // Ks row stride (64+8)
#define LDV 136   // Vs/Ps row stride (128+8)
__global__ __launch_bounds__(256) void flash_k(
    const u16* __restrict__ qh, const u16* __restrict__ kh, const u16* __restrict__ vt,
    const uint64_t* __restrict__ maskbits, u16* __restrict__ ctx,
    float* __restrict__ statsM, float* __restrict__ statsL)
{
  const int b = blockIdx.z, h = blockIdx.y, q0 = blockIdx.x * 64;
  const int t = threadIdx.x, wave = t >> 6, lane = t & 63, quad = lane >> 4, mm = lane & 15;
  __shared__ __align__(16) u16 Ks[128 * LDK];        // [key][d]
  __shared__ __align__(16) u16 Vs[64 * LDV];         // [d][key]
  __shared__ __align__(16) u16 Ps[4][16 * LDV];      // per-wave P: [q][key]
  const u16* qb = qh + (size_t)((b * 16 + h) * 2048) * 64;
  const u16* kb = kh + (size_t)((b * 16 + h) * 2048) * 64;
  const u16* vb = vt + (size_t)((b * 16 + h) * 64) * 2048;
  const int qrow = q0 + wave * 16 + mm;
  short8 qa0 = ld8(&qb[qrow * 64 + quad * 8]);
  short8 qa1 = ld8(&qb[qrow * 64 + 32 + quad * 8]);
  f32x4 O[4];
  float mr[4], lrn[4];
  for (int cb = 0; cb < 4; cb++) O[cb] = (f32x4){0.f,0.f,0.f,0.f};
  for (int r = 0; r < 4; r++){ mr[r] = -1e30f; lrn[r] = 0.f; }
  const int qg0 = q0 + wave * 16 + quad * 4;
  const uint64_t* mwb = maskbits + (size_t)(b * 2048) * 32;
  u16* Pw = &Ps[wave][0];

  for (int kt = 0; kt < 16; kt++){
    const int k0 = kt * 128;
    __syncthreads();
    // stage K: 128x64 (1024 chunks of 8), 4 per thread
    #pragma unroll
    for (int i = 0; i < 4; i++){
      int ch = t + i * 256;
      int row = ch >> 3, c8 = (ch & 7) * 8;
      *(short8*)&Ks[row * LDK + c8] = ld8(&kb[(k0 + row) * 64 + c8]);
    }
    // stage V^T: 64x128 (1024 chunks), 4 per thread
    #pragma unroll
    for (int i = 0; i < 4; i++){
      int ch = t + i * 256;
      int row = ch >> 4, c8 = (ch & 15) * 8;
      *(short8*)&Vs[row * LDV + c8] = ld8(&vb[row * 2048 + k0 + c8]);
    }
    __syncthreads();
    // S = Q K^T  (16 q-rows x 128 keys as 8 col-blocks)
    f32x4 S[8];
    #pragma unroll
    for (int cb = 0; cb < 8; cb++){
      S[cb] = (f32x4){0.f,0.f,0.f,0.f};
      short8 kb0 = *(const short8*)&Ks[(cb * 16 + mm) * LDK + quad * 8];
      short8 kb1 = *(const short8*)&Ks[(cb * 16 + mm) * LDK + 32 + quad * 8];
      S[cb] = MFMA(qa0, kb0, S[cb]);
      S[cb] = MFMA(qa1, kb1, S[cb]);
    }
    // mask: bit set => masked (2 words of 64 bits per row per 128-key tile)
    uint64_t wb[4][2];
    #pragma unroll
    for (int r = 0; r < 4; r++){
      wb[r][0] = mwb[(size_t)(qg0 + r) * 32 + (k0 >> 6)];
      wb[r][1] = mwb[(size_t)(qg0 + r) * 32 + (k0 >> 6) + 1];
    }
    #pragma unroll
    for (int cb = 0; cb < 8; cb++)
      #pragma unroll
      for (int r = 0; r < 4; r++)
        if ((wb[r][cb >> 2] >> ((cb & 3) * 16 + mm)) & 1ull) S[cb][r] = -1e30f;
    // online softmax per row r (16 lanes of the quad hold one row)
    #pragma unroll
    for (int r = 0; r < 4; r++){
      float tmax = S[0][r];
      #pragma unroll
      for (int cb = 1; cb < 8; cb++) tmax = fmaxf(tmax, S[cb][r]);
      for (int off = 1; off < 16; off <<= 1) tmax = fmaxf(tmax, __shfl_xor(tmax, off, 64));
      float mnew  = fmaxf(mr[r], tmax);
      float alpha = __expf(mr[r] - mnew);
      float tsum = 0.f;
      #pragma unroll
      for (int cb = 0; cb < 8; cb++){
        float p = (S[cb][r] > -1e29f) ? __expf(S[cb][r] - mnew) : 0.f;
        S[cb][r] = p; tsum += p;
      }
      for (int off = 1; off < 16; off <<= 1) tsum += __shfl_xor(tsum, off, 64);
      lrn[r] = lrn[r] * alpha + tsum;
      mr[r]  = mnew;
      #pragma unroll
      for (int cb = 0; cb < 4; cb++) O[cb][r] *= alpha;
    }
    // P (C-layout) -> LDS (bf16) -> A-layout frags
    #pragma unroll
    for (int cb = 0; cb < 8; cb++)
      #pragma unroll
      for (int r = 0; r < 4; r++)
        Pw[(quad * 4 + r) * LDV + cb * 16 + mm] = f2bf(S[cb][r]);
    #pragma unroll
    for (int kc = 0; kc < 4; kc++){
      short8 pa = *(const short8*)&Pw[mm * LDV + kc * 32 + quad * 8];
      #pragma unroll
      for (int cb = 0; cb < 4; cb++){
        short8 vv = *(const short8*)&Vs[(cb * 16 + mm) * LDV + kc * 32 + quad * 8];
        O[cb] = MFMA(pa, vv, O[cb]);
      }
    }
  }
  float inv[4];
  for (int r = 0; r < 4; r++) inv[r] = (lrn[r] > 0.f) ? 1.0f / lrn[r] : 0.f;
  #pragma unroll
  for (int cb = 0; cb < 4; cb++)
    #pragma unroll
    for (int r = 0; r < 4; r++){
      int qg = qg0 + r;
      ctx[(size_t)(b * 2048 + qg) * 1024 + h * 64 + cb * 16 + mm] = f2bf(O[cb][r] * inv[r]);
    }
  if (mm == 0){
    for (int r = 0; r < 4; r++){
      statsM[(b * 16 + h) * 2048 + qg0 + r] = mr[r];
      statsL[(b * 16 + h) * 2048 + qg0 + r] = lrn[r];
    }
  }
}

// ---------------------------------------------------------------------------
// Kernel 3: attn_avg[b,q,k] = qmask[b,q] * (1/16) sum_h exp(S-m)/l   (f32 out)
__global__ __launch_bounds__(256) void attnavg_k(
    const u16* __restrict__ qh, const u16* __restrict__ kh,
    const uint64_t* __restrict__ maskbits, const float* __restrict__ statsM,
    const float* __restrict__ statsL, const float* __restrict__ qmask,
    float* __restrict__ out2)
{
  const int b = blockIdx.z, q0 = blockIdx.y * 64, k0 = blockIdx.x * 64;
  const int t = threadIdx.x, wave = t >> 6, lane = t & 63, quad = lane >> 4, mm = lane & 15;
  __shared__ __align__(16) u16 Ks[64 * LDK];
  f32x4 acc[4];
  for (int cb = 0; cb < 4; cb++) acc[cb] = (f32x4){0.f,0.f,0.f,0.f};
  const int qg0 = q0 + wave * 16 + quad * 4;
  uint64_t wb[4];
  for (int r = 0; r < 4; r++)
    wb[r] = maskbits[(size_t)(b * 2048 + qg0 + r) * 32 + (k0 >> 6)];
  const int lr_ = t >> 2, lc_ = (t & 3) * 8;

  for (int h = 0; h < 16; h++){
    const u16* kb = kh + (size_t)((b * 16 + h) * 2048) * 64;
    const u16* qb = qh + (size_t)((b * 16 + h) * 2048) * 64;
    __syncthreads();
    *(short8*)&Ks[lr_ * LDK + lc_]      = ld8(&kb[(k0 + lr_) * 64 + lc_]);
    *(short8*)&Ks[lr_ * LDK + 32 + lc_] = ld8(&kb[(k0 + lr_) * 64 + 32 + lc_]);
    __syncthreads();
    const int qrow = q0 + wave * 16 + mm;
    short8 qa0 = ld8(&qb[qrow * 64 + quad * 8]);
    short8 qa1 = ld8(&qb[qrow * 64 + 32 + quad * 8]);
    f32x4 S[4];
    #pragma unroll
    for (int cb = 0; cb < 4; cb++){
      S[cb] = (f32x4){0.f,0.f,0.f,0.f};
      short8 kb0 = *(const short8*)&Ks[(cb * 16 + mm) * LDK + quad * 8];
      short8 kb1 = *(const short8*)&Ks[(cb * 16 + mm) * LDK + 32 + quad * 8];
      S[cb] = MFMA(qa0, kb0, S[cb]);
      S[cb] = MFMA(qa1, kb1, S[cb]);
    }
    #pragma unroll
    for (int r = 0; r < 4; r++){
      int sidx = (b * 16 + h) * 2048 + qg0 + r;
      float mh = statsM[sidx], lh = statsL[sidx];
      float sc = (lh > 0.f) ? 1.0f / (lh * 16.0f) : 0.f;
      #pragma unroll
      for (int cb = 0; cb < 4; cb++)
        if (!((wb[r] >> (cb * 16 + mm)) & 1ull))
          acc[cb][r] += __expf(S[cb][r] - mh) * sc;
    }
  }
  for (int r = 0; r < 4; r++){
    int qg = qg0 + r;
    float qm = qmask[b * 2048 + qg];
    for (int cb = 0; cb < 4; cb++)
      out2[(size_t)(b * 2048 + qg) * 2048 + k0 + cb * 16 + mm] = acc[cb][r] * qm;
  }
}

// ---------------------------------------------------------------------------
// Kernel 4: final projection (f32 out). out[r,c] = qmask[r]*(sum_d ctx[r,d]*finw[c,d]+b[c])
__global__ __launch_bounds__(256) void fin_gemm_k(
    const u16* __restrict__ A, const float* __restrict__ W, const float* __restrict__ bias,
    const float* __restrict__ qmask, float* __restrict__ out)
{
  const int tileM = blockIdx.y * 64, tileN = blockIdx.x * 64;
  __shared__ __align__(16) u16 As[64 * QLDA];
  __shared__ __align__(16) u16 Bs[64 * QLDA];
  const int t = threadIdx.x, wave = t >> 6, lane = t & 63, quad = lane >> 4, mm = lane & 15;
  const int waveM = (wave >> 1) * 32, waveN = (wave & 1) * 32;
  f32x4 acc[2][2];
  for (int i = 0; i < 2; i++) for (int j = 0; j < 2; j++) acc[i][j] = (f32x4){0.f,0.f,0.f,0.f};
  const int lr = t >> 2, lc = (t & 3) * 8;
  for (int k0 = 0; k0 < 1024; k0 += 32){
    __syncthreads();
    *(short8*)&As[lr * QLDA + lc] = ld8(&A[(size_t)(tileM + lr) * 1024 + k0 + lc]);
    *(short8*)&Bs[lr * QLDA + lc] = ld8f(&W[(size_t)(tileN + lr) * 1024 + k0 + lc]);
    __syncthreads();
    short8 a0 = *(const short8*)&As[(waveM + mm) * QLDA + quad * 8];
    short8 a1 = *(const short8*)&As[(waveM + 16 + mm) * QLDA + quad * 8];
    short8 b0 = *(const short8*)&Bs[(waveN + mm) * QLDA + quad * 8];
    short8 b1 = *(const short8*)&Bs[(waveN + 16 + mm) * QLDA + quad * 8];
    acc[0][0] = MFMA(a0, b0, acc[0][0]);
    acc[0][1] = MFMA(a0, b1, acc[0][1]);
    acc[1][0] = MFMA(a1, b0, acc[1][0]);
    acc[1][1] = MFMA(a1, b1, acc[1][1]);
  }
  for (int i = 0; i < 2; i++) for (int j = 0; j < 2; j++){
    int col = tileN + waveN + j * 16 + mm;
    float bv = bias[col];
    for (int r = 0; r < 4; r++){
      int row = tileM + waveM + i * 16 + quad * 4 + r;
      float v = (acc[i][j][r] + bv) * qmask[row];
      out[(size_t)row * 1024 + col] = v;
    }
  }
}

// ---------------------------------------------------------------------------
extern "C" void kernel_launch(void* const* d_in, const int* in_sizes, int n_in,
                              void* d_out, int out_size, void* d_ws, size_t ws_size,
                              hipStream_t stream) {
  // setup_inputs order: k, v, q, attn_mask, query_mask, kqv_w, kqv_b, fin_w, fin_b
  const float* k_in   = (const float*)d_in[0];
  const float* v_in   = (const float*)d_in[1];
  const float* q_in   = (const float*)d_in[2];
  const int*   amask  = (const int*)d_in[3];
  const float* qmask  = (const float*)d_in[4];
  const float* kqv_w  = (const float*)d_in[5];
  const float* kqv_b  = (const float*)d_in[6];
  const float* fin_w  = (const float*)d_in[7];
  const float* fin_b  = (const float*)d_in[8];
  float* out  = (float*)d_out;                  // out0: [0, 8388608) context (f32)
  float* out2 = out + (size_t)8388608;          // out1: attn_avg (16777216 f32)

  const size_t WS_NEED = 36700160;
  if (ws_size < WS_NEED){
    sentinel_k<<<1, 1, 0, stream>>>(out, 1.0e6f + (float)(ws_size >> 20));
    return;
  }

  // Scratch: 36.7 MB in d_ws; bf16 intermediates parked inside f32 d_out:
  //   vt  (V^T, bf16, 16.7MB)  -> out0 region (fin_gemm overwrites later)
  //   ctx (pre-proj, bf16, 16.7MB) -> out2 region (attnavg overwrites later)
  // Order: maskpack -> qkv -> flash -> fin_gemm (reads ctx) -> attnavg.
  u16* qh  = (u16*)d_ws;                        // 8,388,608 bf16 (16.7 MB), PRE-SCALED by 1/8
  u16* kh  = qh + (size_t)8388608;              // 16.7 MB
  float* statsM = (float*)(kh + (size_t)8388608);    // B*H*L = 131072 f32
  float* statsL = statsM + 131072;
  uint64_t* maskbits = (uint64_t*)(statsL + 131072); // B*L*32 words (2 MB)
  u16* vt  = (u16*)out;                         // scratch in out0
  u16* ctx = (u16*)out2;                        // scratch in out2 (first 16.7MB)

  maskpack_k<<<dim3(65536), dim3(256), 0, stream>>>(amask, maskbits);
  qkv_gemm_k<<<dim3(16, 128, 3), dim3(256), 0, stream>>>(
      k_in, q_in, v_in, kqv_w, kqv_b, qh, kh, vt);
  flash_k<<<dim3(32, 16, 4), dim3(256), 0, stream>>>(
      qh, kh, vt, maskbits, ctx, statsM, statsL);
  fin_gemm_k<<<dim3(16, 128), dim3(256), 0, stream>>>(
      ctx, fin_w, fin_b, qmask, out);
  attnavg_k<<<dim3(32, 32, 4), dim3(256), 0, stream>>>(
      qh, kh, maskbits, statsM, statsL, qmask, out2);
}